// Round 1
// baseline (433.607 us; speedup 1.0000x reference)
//
#include <hip/hip_runtime.h>

// InstantNGP MLP: (N,32) -> [Linear+ReLU]x3 -> Linear -> (N,16), all fp32.
//
// Scheme: transposed MFMA chain with 3-product bf16 hi/lo split (fp32-accurate).
//   - A operand = W^T (staged in LDS as bf16 hi+lo, padded stride, read ds_read_b128)
//   - B operand = activations, col = sample (32 samples per MFMA tile)
//   - layer->layer feature movement stays in-register: pack_hi16 + permlane32_swap
//     (features only cross lane-halves in the 32x32 C layout; no LDS roundtrip)
//   - acc init = bias (broadcast b128 from LDS); relu on acc; final store dwordx4.
// Per wave-iteration: 64 samples (2 groups of 32), weights amortized across groups.
// Block = 4 waves; block handles ITERS*256 = 512 samples; grid = N/512 = 2048.

typedef float f32x4 __attribute__((ext_vector_type(4)));
typedef float f32x16 __attribute__((ext_vector_type(16)));
typedef short short8 __attribute__((ext_vector_type(8)));

#define DEVFN static __device__ __forceinline__

// truncation split: hi = top16 bits of f32 (bf16, toward-zero), lo = exact residual
DEVFN unsigned pack_hi16(float a, float b) {
  return (__float_as_uint(a) >> 16) | (__float_as_uint(b) & 0xffff0000u);
}
DEVFN float lo_part(float a) {
  return a - __uint_as_float(__float_as_uint(a) & 0xffff0000u);
}

union Frag {
  unsigned u[4];
  short8 s;
};

// Produce (word_w, word_{w+2}) of a B-frag from the h0-variant pack q (regs +0,+1)
// and h1-variant pack p (regs +4,+5). One permlane32_swap yields both words
// (m214 v22 pattern). Fallback: shfl_xor(32) + select (semantics-unambiguous).
DEVFN void half_swap(unsigned q, unsigned p, unsigned& wlo, unsigned& whi,
                     unsigned laneHi) {
#if __has_builtin(__builtin_amdgcn_permlane32_swap)
  (void)laneHi;
  auto r = __builtin_amdgcn_permlane32_swap(q, p, false, false);
  wlo = (unsigned)r[0];
  whi = (unsigned)r[1];
#else
  unsigned qs = (unsigned)__shfl_xor((int)q, 32, 64);
  unsigned ps = (unsigned)__shfl_xor((int)p, 32, 64);
  wlo = laneHi ? ps : q;
  whi = laneHi ? p : qs;
#endif
}

// C-regs (c0..c7 = acc regs b0..b0+7 of one tile) -> next-layer B frag (hi,lo).
DEVFN void build_frags_swap(float c0, float c1, float c2, float c3, float c4,
                            float c5, float c6, float c7, Frag& hi, Frag& lo,
                            unsigned laneHi) {
  half_swap(pack_hi16(c0, c1), pack_hi16(c4, c5), hi.u[0], hi.u[2], laneHi);
  half_swap(pack_hi16(c2, c3), pack_hi16(c6, c7), hi.u[1], hi.u[3], laneHi);
  half_swap(pack_hi16(lo_part(c0), lo_part(c1)),
            pack_hi16(lo_part(c4), lo_part(c5)), lo.u[0], lo.u[2], laneHi);
  half_swap(pack_hi16(lo_part(c2), lo_part(c3)),
            pack_hi16(lo_part(c6), lo_part(c7)), lo.u[1], lo.u[3], laneHi);
}

// x row chunk (8 floats: a=j0..3, b=j4..7) -> layer-1 B frag (no cross-lane needed)
DEVFN void build_frags_direct(f32x4 a, f32x4 b, Frag& hi, Frag& lo) {
  hi.u[0] = pack_hi16(a.x, a.y);
  hi.u[1] = pack_hi16(a.z, a.w);
  hi.u[2] = pack_hi16(b.x, b.y);
  hi.u[3] = pack_hi16(b.z, b.w);
  lo.u[0] = pack_hi16(lo_part(a.x), lo_part(a.y));
  lo.u[1] = pack_hi16(lo_part(a.z), lo_part(a.w));
  lo.u[2] = pack_hi16(lo_part(b.x), lo_part(b.y));
  lo.u[3] = pack_hi16(lo_part(b.z), lo_part(b.w));
}

DEVFN f32x16 mfma32(short8 a, short8 b, f32x16 c) {
  return __builtin_amdgcn_mfma_f32_32x32x16_bf16(a, b, c, 0, 0, 0);
}

#define ITERS 2

__global__ __launch_bounds__(256, 2) void ngp_mlp_kernel(
    const float* __restrict__ x, const float* __restrict__ Win,
    const float* __restrict__ bin, const float* __restrict__ W1,
    const float* __restrict__ b1, const float* __restrict__ W2,
    const float* __restrict__ b2, const float* __restrict__ Wout,
    const float* __restrict__ bout, float* __restrict__ out) {
  // W^T in LDS, bf16 hi/lo, padded strides (40 for K=32, 72 for K=64):
  // stride/8 odd -> conflict-free-ish ds_read_b128. ~52.5 KB total.
  __shared__ __align__(16) unsigned short w1h[64 * 40], w1l[64 * 40];
  __shared__ __align__(16) unsigned short w2h[64 * 72], w2l[64 * 72];
  __shared__ __align__(16) unsigned short w3h[64 * 72], w3l[64 * 72];
  __shared__ __align__(16) unsigned short w4h[16 * 72], w4l[16 * 72];
  __shared__ __align__(16) float bsh[208];  // b_in | b1 | b2 | b_out

  const int tid = threadIdx.x;

  // ---- stage weights (transpose + split) ----
  for (int e = tid; e < 32 * 64; e += 256) {  // W_in (32,64)
    float w = Win[e];
    int k = e >> 6, m = e & 63;
    w1h[m * 40 + k] = (unsigned short)(__float_as_uint(w) >> 16);
    w1l[m * 40 + k] = (unsigned short)(__float_as_uint(lo_part(w)) >> 16);
  }
  for (int e = tid; e < 64 * 64; e += 256) {  // W1 (64,64)
    float w = W1[e];
    int k = e >> 6, m = e & 63;
    w2h[m * 72 + k] = (unsigned short)(__float_as_uint(w) >> 16);
    w2l[m * 72 + k] = (unsigned short)(__float_as_uint(lo_part(w)) >> 16);
  }
  for (int e = tid; e < 64 * 64; e += 256) {  // W2 (64,64)
    float w = W2[e];
    int k = e >> 6, m = e & 63;
    w3h[m * 72 + k] = (unsigned short)(__float_as_uint(w) >> 16);
    w3l[m * 72 + k] = (unsigned short)(__float_as_uint(lo_part(w)) >> 16);
  }
  for (int e = tid; e < 64 * 16; e += 256) {  // W_out (64,16)
    float w = Wout[e];
    int k = e >> 4, m = e & 15;
    w4h[m * 72 + k] = (unsigned short)(__float_as_uint(w) >> 16);
    w4l[m * 72 + k] = (unsigned short)(__float_as_uint(lo_part(w)) >> 16);
  }
  if (tid < 64) {
    bsh[tid] = bin[tid];
    bsh[64 + tid] = b1[tid];
    bsh[128 + tid] = b2[tid];
    if (tid < 16) bsh[192 + tid] = bout[tid];
  }
  __syncthreads();

  const int wave = tid >> 6;
  const int lane = tid & 63;
  const int ln = lane & 31;                        // sample-in-group / A-row
  const unsigned hH = (unsigned)((lane >> 5) & 1); // lane half
  const int kb = 8 * (int)hH;                      // k offset of this half

  Frag bh[2][4], bl[2][4];  // [group][kappa] current-layer B frags

  for (int it = 0; it < ITERS; ++it) {
    const long srow = ((long)(blockIdx.x * ITERS + it) * 4 + wave) * 64;

    // ---- load x, build layer-1 B frags (K=32 -> kappa 0..1) ----
#pragma unroll
    for (int g = 0; g < 2; ++g) {
      const float* xp = x + (size_t)(srow + g * 32 + ln) * 32 + kb;
      f32x4 v0 = *(const f32x4*)(xp + 0);
      f32x4 v1 = *(const f32x4*)(xp + 4);
      f32x4 v2 = *(const f32x4*)(xp + 16);
      f32x4 v3 = *(const f32x4*)(xp + 20);
      build_frags_direct(v0, v1, bh[g][0], bl[g][0]);
      build_frags_direct(v2, v3, bh[g][1], bl[g][1]);
    }

    // ---- layer 1: 32 -> 64, relu ----
    {
      f32x16 acc[2][2];
#pragma unroll
      for (int T = 0; T < 2; ++T) {
        f32x16 bi;
#pragma unroll
        for (int cq = 0; cq < 4; ++cq) {
          f32x4 bb = *(const f32x4*)&bsh[32 * T + 8 * cq + 4 * (int)hH];
          bi[4 * cq + 0] = bb.x;
          bi[4 * cq + 1] = bb.y;
          bi[4 * cq + 2] = bb.z;
          bi[4 * cq + 3] = bb.w;
        }
        acc[0][T] = bi;
        acc[1][T] = bi;
      }
#pragma unroll
      for (int T = 0; T < 2; ++T) {
#pragma unroll
        for (int ka = 0; ka < 2; ++ka) {
          const int off = (32 * T + ln) * 40 + 16 * ka + kb;
          const short8 ah = *(const short8*)&w1h[off];
          const short8 al = *(const short8*)&w1l[off];
#pragma unroll
          for (int g = 0; g < 2; ++g) {
            acc[g][T] = mfma32(al, bh[g][ka].s, acc[g][T]);
            acc[g][T] = mfma32(ah, bl[g][ka].s, acc[g][T]);
            acc[g][T] = mfma32(ah, bh[g][ka].s, acc[g][T]);
          }
        }
      }
#pragma unroll
      for (int g = 0; g < 2; ++g) {
#pragma unroll
        for (int T = 0; T < 2; ++T)
#pragma unroll
          for (int i = 0; i < 16; ++i) acc[g][T][i] = fmaxf(acc[g][T][i], 0.0f);
#pragma unroll
        for (int ka = 0; ka < 4; ++ka) {
          const int t = ka >> 1, b0 = (ka & 1) * 8;
          build_frags_swap(acc[g][t][b0 + 0], acc[g][t][b0 + 1],
                           acc[g][t][b0 + 2], acc[g][t][b0 + 3],
                           acc[g][t][b0 + 4], acc[g][t][b0 + 5],
                           acc[g][t][b0 + 6], acc[g][t][b0 + 7], bh[g][ka],
                           bl[g][ka], hH);
        }
      }
    }

    // ---- layers 2,3: 64 -> 64 ----
    auto layer64 = [&](const unsigned short* wh, const unsigned short* wl,
                       int boff) {
      f32x16 acc[2][2];
#pragma unroll
      for (int T = 0; T < 2; ++T) {
        f32x16 bi;
#pragma unroll
        for (int cq = 0; cq < 4; ++cq) {
          f32x4 bb = *(const f32x4*)&bsh[boff + 32 * T + 8 * cq + 4 * (int)hH];
          bi[4 * cq + 0] = bb.x;
          bi[4 * cq + 1] = bb.y;
          bi[4 * cq + 2] = bb.z;
          bi[4 * cq + 3] = bb.w;
        }
        acc[0][T] = bi;
        acc[1][T] = bi;
      }
#pragma unroll
      for (int T = 0; T < 2; ++T) {
#pragma unroll
        for (int ka = 0; ka < 4; ++ka) {
          const int off = (32 * T + ln) * 72 + 16 * ka + kb;
          const short8 ah = *(const short8*)&wh[off];
          const short8 al = *(const short8*)&wl[off];
#pragma unroll
          for (int g = 0; g < 2; ++g) {
            acc[g][T] = mfma32(al, bh[g][ka].s, acc[g][T]);
            acc[g][T] = mfma32(ah, bl[g][ka].s, acc[g][T]);
            acc[g][T] = mfma32(ah, bh[g][ka].s, acc[g][T]);
          }
        }
      }
#pragma unroll
      for (int g = 0; g < 2; ++g) {
#pragma unroll
        for (int T = 0; T < 2; ++T)
#pragma unroll
          for (int i = 0; i < 16; ++i) acc[g][T][i] = fmaxf(acc[g][T][i], 0.0f);
#pragma unroll
        for (int ka = 0; ka < 4; ++ka) {
          const int t = ka >> 1, b0 = (ka & 1) * 8;
          build_frags_swap(acc[g][t][b0 + 0], acc[g][t][b0 + 1],
                           acc[g][t][b0 + 2], acc[g][t][b0 + 3],
                           acc[g][t][b0 + 4], acc[g][t][b0 + 5],
                           acc[g][t][b0 + 6], acc[g][t][b0 + 7], bh[g][ka],
                           bl[g][ka], hH);
        }
      }
    };
    layer64(w2h, w2l, 64);
    layer64(w3h, w3l, 128);

    // ---- layer 4: 64 -> 16 (M padded to 32 via row duplication), no relu ----
    f32x16 a4[2];
    {
      f32x16 bi;
      f32x4 q0 = *(const f32x4*)&bsh[192 + 4 * (int)hH];
      f32x4 q1 = *(const f32x4*)&bsh[192 + 8 + 4 * (int)hH];
      bi[0] = q0.x; bi[1] = q0.y; bi[2] = q0.z; bi[3] = q0.w;
      bi[4] = q1.x; bi[5] = q1.y; bi[6] = q1.z; bi[7] = q1.w;
#pragma unroll
      for (int i = 8; i < 16; ++i) bi[i] = 0.0f;
      a4[0] = bi;
      a4[1] = bi;
    }
#pragma unroll
    for (int ka = 0; ka < 4; ++ka) {
      const int off = (ln & 15) * 72 + 16 * ka + kb;
      const short8 ah = *(const short8*)&w4h[off];
      const short8 al = *(const short8*)&w4l[off];
#pragma unroll
      for (int g = 0; g < 2; ++g) {
        a4[g] = mfma32(al, bh[g][ka].s, a4[g]);
        a4[g] = mfma32(ah, bl[g][ka].s, a4[g]);
        a4[g] = mfma32(ah, bh[g][ka].s, a4[g]);
      }
    }

    // ---- store: lane(h,n) holds features 4h..4h+3 (regs 0-3), 8+4h.. (regs 4-7)
#pragma unroll
    for (int g = 0; g < 2; ++g) {
      float* op = out + (size_t)(srow + g * 32 + ln) * 16 + 4 * (int)hH;
      f32x4 s0 = {a4[g][0], a4[g][1], a4[g][2], a4[g][3]};
      f32x4 s1 = {a4[g][4], a4[g][5], a4[g][6], a4[g][7]};
      *(f32x4*)(op + 0) = s0;
      *(f32x4*)(op + 8) = s1;
    }
  }
}

extern "C" void kernel_launch(void* const* d_in, const int* in_sizes, int n_in,
                              void* d_out, int out_size, void* d_ws,
                              size_t ws_size, hipStream_t stream) {
  (void)n_in;
  (void)out_size;
  (void)d_ws;
  (void)ws_size;
  const float* x = (const float*)d_in[0];
  const float* Win = (const float*)d_in[1];
  const float* bin = (const float*)d_in[2];
  const float* W1 = (const float*)d_in[3];
  const float* b1 = (const float*)d_in[4];
  const float* W2 = (const float*)d_in[5];
  const float* b2 = (const float*)d_in[6];
  const float* Wout = (const float*)d_in[7];
  const float* bout = (const float*)d_in[8];
  float* out = (float*)d_out;

  const int nrows = in_sizes[0] / 32;          // 1048576
  const int blocks = nrows / (ITERS * 256);    // 512 samples per block -> 2048
  ngp_mlp_kernel<<<blocks, 256, 0, stream>>>(x, Win, bin, W1, b1, W2, b2, Wout,
                                             bout, out);
}